// Round 2
// baseline (1215.902 us; speedup 1.0000x reference)
//
#include <hip/hip_runtime.h>
#include <math.h>

// Problem constants (B=2, S=1024, H=12, HS=64, ALL=768, P=128)
#define SEQ   1024
#define BATCH 2
#define NH    12
#define HS_   64
#define ALLD  768
#define ALL2  1536
// 1/scaling = 1/64^0.25
#define INVS  0.35355339059327373f

typedef __attribute__((ext_vector_type(8)))  __bf16 bf16x8;
typedef __attribute__((ext_vector_type(4)))  __bf16 bf16x4;
typedef __attribute__((ext_vector_type(16))) float  f32x16;

// ---------------------------------------------------------------------------
// K1: u = p1 @ W_qk + b_qk ; q = u[:, :768]*INVS ; k = u[:, 768:]*INVS
// Outputs:
//   qo : fp32 q row-major [b*S][768]            (for QR kernel)
//   qf : bf16 q in MFMA A-frag layout [b][h][ks][half][s][8]
//   kf : bf16 k in MFMA B-frag layout [b][h][ks][half][t][8]
// M = B*S = 2048, N = 1536, K = 768. 64x64 tile, 256 thr, 4x4 per thread.
// ---------------------------------------------------------------------------
__global__ __launch_bounds__(256) void qk_gemm(
    const float* __restrict__ p1, const float* __restrict__ Wqk,
    const float* __restrict__ bqk, float* __restrict__ qo,
    __bf16* __restrict__ qf, __bf16* __restrict__ kf) {
  const int tid = threadIdx.x;
  const int tx = tid & 15, ty = tid >> 4;
  const int m0 = blockIdx.x * 64;
  const int n0 = blockIdx.y * 64;

  __shared__ float As[16][64];  // [k][m]
  __shared__ float Bs[16][64];  // [k][n]

  float acc[4][4];
#pragma unroll
  for (int i = 0; i < 4; ++i)
#pragma unroll
    for (int j = 0; j < 4; ++j) acc[i][j] = 0.f;

  const int lm = tid >> 2;         // 0..63 A row
  const int lk = (tid & 3) * 4;    // 0,4,8,12
  const int bk = tid >> 4;         // 0..15 B row
  const int bn = (tid & 15) * 4;   // 0..60

  for (int kk = 0; kk < 768; kk += 16) {
    float4 av = *(const float4*)(p1 + (size_t)(m0 + lm) * 768 + kk + lk);
    float4 bv = *(const float4*)(Wqk + (size_t)(kk + bk) * 1536 + n0 + bn);
    __syncthreads();
    As[lk + 0][lm] = av.x;
    As[lk + 1][lm] = av.y;
    As[lk + 2][lm] = av.z;
    As[lk + 3][lm] = av.w;
    *(float4*)&Bs[bk][bn] = bv;
    __syncthreads();
#pragma unroll
    for (int kq = 0; kq < 16; ++kq) {
      float4 a = *(const float4*)&As[kq][ty * 4];
      float4 b = *(const float4*)&Bs[kq][tx * 4];
      acc[0][0] += a.x * b.x; acc[0][1] += a.x * b.y;
      acc[0][2] += a.x * b.z; acc[0][3] += a.x * b.w;
      acc[1][0] += a.y * b.x; acc[1][1] += a.y * b.y;
      acc[1][2] += a.y * b.z; acc[1][3] += a.y * b.w;
      acc[2][0] += a.z * b.x; acc[2][1] += a.z * b.y;
      acc[2][2] += a.z * b.z; acc[2][3] += a.z * b.w;
      acc[3][0] += a.w * b.x; acc[3][1] += a.w * b.y;
      acc[3][2] += a.w * b.z; acc[3][3] += a.w * b.w;
    }
  }

  // epilogue: bias + scale, write fp32 q rows + bf16 fragment layouts
  const int n_base = n0 + tx * 4;            // aligned to 4
  const bool is_q = (n_base < ALLD);
  const int nn = is_q ? n_base : n_base - ALLD;
  const int h = nn >> 6;
  const int dd = nn & 63;
  const int ks = dd >> 4;
  const int half = (dd >> 3) & 1;
  const int e = dd & 7;                       // 0 or 4

#pragma unroll
  for (int i = 0; i < 4; ++i) {
    const int m = m0 + ty * 4 + i;
    const int bb = m >> 10;
    const int ss = m & 1023;
    float4 vf;
    bf16x4 vb;
    float v0 = (acc[i][0] + bqk[n_base + 0]) * INVS;
    float v1 = (acc[i][1] + bqk[n_base + 1]) * INVS;
    float v2 = (acc[i][2] + bqk[n_base + 2]) * INVS;
    float v3 = (acc[i][3] + bqk[n_base + 3]) * INVS;
    vf.x = v0; vf.y = v1; vf.z = v2; vf.w = v3;
    vb[0] = (__bf16)v0; vb[1] = (__bf16)v1;
    vb[2] = (__bf16)v2; vb[3] = (__bf16)v3;
    const size_t fidx =
        ((((size_t)(bb * NH + h) * 4 + ks) * 2 + half) * SEQ + ss) * 8 + e;
    if (is_q) {
      *(float4*)(qo + (size_t)m * ALLD + n_base) = vf;
      *(bf16x4*)(qf + fidx) = vb;
    } else {
      *(bf16x4*)(kf + fidx) = vb;
    }
  }
}

// ---------------------------------------------------------------------------
// K2: QR[b,s,id,h] = sum_d q[b,s,h*64+d] * rel_emb[id,d] * INVS
// One block per (b*S + s); thread = id (256 ids).
// ---------------------------------------------------------------------------
__global__ __launch_bounds__(256) void qr_kernel(
    const float* __restrict__ q, const float* __restrict__ rel,
    float* __restrict__ QR) {
  const int bs = blockIdx.x;  // 0..2047
  const int tid = threadIdx.x;

  __shared__ float qs[768];
  qs[tid] = q[(size_t)bs * 768 + tid];
  qs[tid + 256] = q[(size_t)bs * 768 + tid + 256];
  qs[tid + 512] = q[(size_t)bs * 768 + tid + 512];
  __syncthreads();

  const float* rrow = rel + (size_t)tid * 64;
  float o[12];
#pragma unroll
  for (int h = 0; h < 12; ++h) o[h] = 0.f;

#pragma unroll
  for (int d4 = 0; d4 < 64; d4 += 4) {
    float4 rv = *(const float4*)(rrow + d4);
#pragma unroll
    for (int h = 0; h < 12; ++h) {
      o[h] += qs[h * 64 + d4 + 0] * rv.x + qs[h * 64 + d4 + 1] * rv.y +
              qs[h * 64 + d4 + 2] * rv.z + qs[h * 64 + d4 + 3] * rv.w;
    }
  }

  float* dst = QR + ((size_t)bs * 256 + tid) * 12;
#pragma unroll
  for (int h = 0; h < 12; h += 4) {
    float4 v;
    v.x = o[h + 0] * INVS;
    v.y = o[h + 1] * INVS;
    v.z = o[h + 2] * INVS;
    v.w = o[h + 3] * INVS;
    *(float4*)(dst + h) = v;
  }
}

// ---------------------------------------------------------------------------
// K3: fused scores (MFMA) + QR bias + writer + store.
// Block = 256 thr (4 waves). Tile: 32 s x 128 t; wave w owns t-subtile
// [t0+32w, t0+32w+32), all 12 heads (12 x f32x16 accumulators).
// Fragments come straight from global (qf/kf frag layout, coalesced, L2-hot).
// C layout (verified m74/m101): col=lane&31 (t), row=(reg&3)+8*(reg>>2)+
// 4*(lane>>5) (s-offset).
// ---------------------------------------------------------------------------
__global__ __launch_bounds__(256, 1) void main_kernel(
    const __bf16* __restrict__ qf, const __bf16* __restrict__ kf,
    const float* __restrict__ QR, const float* __restrict__ Wout,
    const float* __restrict__ bout, float* __restrict__ out) {
  const int tid = threadIdx.x;
  const int l = tid & 63;
  const int w = tid >> 6;
  const int b = blockIdx.z;
  const int s0 = blockIdx.y * 32;
  const int t0 = blockIdx.x * 128 + w * 32;

  __shared__ float Wl[12][64];
  __shared__ float bol[64];
#pragma unroll
  for (int r = 0; r < 3; ++r) ((float*)Wl)[tid + 256 * r] = Wout[tid + 256 * r];
  if (tid < 64) bol[tid] = bout[tid];
  __syncthreads();

  const int half = l >> 5;
  const int lane31 = l & 31;
  const int qrow = s0 + lane31;
  const int trow = t0 + lane31;

  f32x16 zz;
#pragma unroll
  for (int e = 0; e < 16; ++e) zz[e] = 0.f;
  f32x16 acc[12];
#pragma unroll
  for (int h = 0; h < 12; ++h) acc[h] = zz;

  const bf16x8* qfp = (const bf16x8*)qf;
  const bf16x8* kfp = (const bf16x8*)kf;

  // -------- scores via MFMA: 12 heads x 4 K-steps --------
#pragma unroll
  for (int h = 0; h < 12; ++h) {
#pragma unroll
    for (int ks = 0; ks < 4; ++ks) {
      const size_t pbase = (((size_t)(b * NH + h) * 4 + ks) * 2 + half) * SEQ;
      bf16x8 af = qfp[pbase + qrow];
      bf16x8 bf = kfp[pbase + trow];
      acc[h] = __builtin_amdgcn_mfma_f32_32x32x16_bf16(af, bf, acc[h], 0, 0, 0);
    }
  }

  // -------- bias: QR[b,s,id(t-s),0..11] gathers --------
  const int t = t0 + lane31;
  const int srowbase = s0 + 4 * half;
#pragma unroll
  for (int r = 0; r < 16; ++r) {
    const int s = srowbase + (r & 3) + 8 * (r >> 2);
    const int d = t - s;
    const int id = (d >= 0) ? (d < 127 ? d : 127)
                            : (d > -127 ? d + 256 : 129);
    const float4* qrp =
        (const float4*)(QR + ((size_t)((b << 10) + s) * 256 + id) * 12);
    float4 r0 = qrp[0];
    float4 r1 = qrp[1];
    float4 r2 = qrp[2];
    float qrv[12];
    qrv[0] = r0.x; qrv[1] = r0.y; qrv[2]  = r0.z; qrv[3]  = r0.w;
    qrv[4] = r1.x; qrv[5] = r1.y; qrv[6]  = r1.z; qrv[7]  = r1.w;
    qrv[8] = r2.x; qrv[9] = r2.y; qrv[10] = r2.z; qrv[11] = r2.w;
#pragma unroll
    for (int h = 0; h < 12; ++h) acc[h][r] += qrv[h];
  }

  // -------- writer: out[b,s,t,c] = sum_h A[h]*W[h,c] + b[c] --------
  // c4 is a runtime loop (keeps I$ small); r,h unrolled (acc reg-resident).
  float* obase = out + (((size_t)((b << 10))) << 10) * 64;
#pragma unroll 1
  for (int c4 = 0; c4 < 16; ++c4) {
    float4 w4[12];
#pragma unroll
    for (int h = 0; h < 12; ++h) w4[h] = *(const float4*)&Wl[h][c4 * 4];
    const float4 bo = *(const float4*)&bol[c4 * 4];
#pragma unroll
    for (int r = 0; r < 16; ++r) {
      const int s = srowbase + (r & 3) + 8 * (r >> 2);
      float4 o = bo;
#pragma unroll
      for (int h = 0; h < 12; ++h) {
        const float a = acc[h][r];
        o.x += a * w4[h].x;
        o.y += a * w4[h].y;
        o.z += a * w4[h].z;
        o.w += a * w4[h].w;
      }
      *(float4*)(obase + (((size_t)s << 10) + t) * 64 + c4 * 4) = o;
    }
  }
}

// ---------------------------------------------------------------------------
extern "C" void kernel_launch(void* const* d_in, const int* in_sizes, int n_in,
                              void* d_out, int out_size, void* d_ws,
                              size_t ws_size, hipStream_t stream) {
  const float* p1 = (const float*)d_in[1];
  const float* Wqk = (const float*)d_in[3];
  const float* bqk = (const float*)d_in[4];
  const float* rel = (const float*)d_in[5];
  const float* Wout = (const float*)d_in[6];
  const float* bout = (const float*)d_in[7];
  float* out = (float*)d_out;

  // workspace layout:
  //   qo  fp32 [2*1024*768]            6.29 MB
  //   qf  bf16 frag [2*1024*768]       3.15 MB
  //   kf  bf16 frag [2*1024*768]       3.15 MB
  //   QR  fp32 [2*1024*256*12]        25.17 MB   (total 37.75 MB)
  float* qo = (float*)d_ws;
  __bf16* qf = (__bf16*)(qo + (size_t)BATCH * SEQ * ALLD);
  __bf16* kf = qf + (size_t)BATCH * SEQ * ALLD;
  float* QR = (float*)(kf + (size_t)BATCH * SEQ * ALLD);

  hipLaunchKernelGGL(qk_gemm, dim3(32, 24), dim3(256), 0, stream, p1, Wqk, bqk,
                     qo, qf, kf);
  hipLaunchKernelGGL(qr_kernel, dim3(BATCH * SEQ), dim3(256), 0, stream, qo,
                     rel, QR);
  hipLaunchKernelGGL(main_kernel, dim3(SEQ / 128, SEQ / 32, BATCH), dim3(256),
                     0, stream, qf, kf, QR, Wout, bout, out);
}

// Round 3
// 287.737 us; speedup vs baseline: 4.2257x; 4.2257x over previous
//
#include <hip/hip_runtime.h>
#include <math.h>

// Problem constants (B=2, S=1024, H=12, HS=64, ALL=768, P=128)
#define SEQ   1024
#define BATCH 2
#define NH    12
#define HS_   64
#define ALLD  768
#define ALL2  1536
// 1/scaling = 1/64^0.25
#define INVS  0.35355339059327373f

typedef __attribute__((ext_vector_type(8)))  __bf16 bf16x8;
typedef __attribute__((ext_vector_type(4)))  __bf16 bf16x4;
typedef __attribute__((ext_vector_type(16))) float  f32x16;

// ---------------------------------------------------------------------------
// K1: u = p1 @ W_qk + b_qk ; q = u[:, :768]*INVS ; k = u[:, 768:]*INVS
// Outputs:
//   qo : fp32 q row-major [b*S][768]            (for QR kernel)
//   qf : bf16 q in MFMA A-frag layout [b][h][ks][half][s][8]
//   kf : bf16 k in MFMA B-frag layout [b][h][ks][half][t][8]
// ---------------------------------------------------------------------------
__global__ __launch_bounds__(256) void qk_gemm(
    const float* __restrict__ p1, const float* __restrict__ Wqk,
    const float* __restrict__ bqk, float* __restrict__ qo,
    __bf16* __restrict__ qf, __bf16* __restrict__ kf) {
  const int tid = threadIdx.x;
  const int tx = tid & 15, ty = tid >> 4;
  const int m0 = blockIdx.x * 64;
  const int n0 = blockIdx.y * 64;

  __shared__ float As[16][64];  // [k][m]
  __shared__ float Bs[16][64];  // [k][n]

  float acc[4][4];
#pragma unroll
  for (int i = 0; i < 4; ++i)
#pragma unroll
    for (int j = 0; j < 4; ++j) acc[i][j] = 0.f;

  const int lm = tid >> 2;         // 0..63 A row
  const int lk = (tid & 3) * 4;    // 0,4,8,12
  const int bk = tid >> 4;         // 0..15 B row
  const int bn = (tid & 15) * 4;   // 0..60

  for (int kk = 0; kk < 768; kk += 16) {
    float4 av = *(const float4*)(p1 + (size_t)(m0 + lm) * 768 + kk + lk);
    float4 bv = *(const float4*)(Wqk + (size_t)(kk + bk) * 1536 + n0 + bn);
    __syncthreads();
    As[lk + 0][lm] = av.x;
    As[lk + 1][lm] = av.y;
    As[lk + 2][lm] = av.z;
    As[lk + 3][lm] = av.w;
    *(float4*)&Bs[bk][bn] = bv;
    __syncthreads();
#pragma unroll
    for (int kq = 0; kq < 16; ++kq) {
      float4 a = *(const float4*)&As[kq][ty * 4];
      float4 b = *(const float4*)&Bs[kq][tx * 4];
      acc[0][0] += a.x * b.x; acc[0][1] += a.x * b.y;
      acc[0][2] += a.x * b.z; acc[0][3] += a.x * b.w;
      acc[1][0] += a.y * b.x; acc[1][1] += a.y * b.y;
      acc[1][2] += a.y * b.z; acc[1][3] += a.y * b.w;
      acc[2][0] += a.z * b.x; acc[2][1] += a.z * b.y;
      acc[2][2] += a.z * b.z; acc[2][3] += a.z * b.w;
      acc[3][0] += a.w * b.x; acc[3][1] += a.w * b.y;
      acc[3][2] += a.w * b.z; acc[3][3] += a.w * b.w;
    }
  }

  // epilogue: bias + scale, write fp32 q rows + bf16 fragment layouts
  const int n_base = n0 + tx * 4;            // aligned to 4
  const bool is_q = (n_base < ALLD);
  const int nn = is_q ? n_base : n_base - ALLD;
  const int h = nn >> 6;
  const int dd = nn & 63;
  const int ks = dd >> 4;
  const int half = (dd >> 3) & 1;
  const int e = dd & 7;                       // 0 or 4

#pragma unroll
  for (int i = 0; i < 4; ++i) {
    const int m = m0 + ty * 4 + i;
    const int bb = m >> 10;
    const int ss = m & 1023;
    float4 vf;
    bf16x4 vb;
    float v0 = (acc[i][0] + bqk[n_base + 0]) * INVS;
    float v1 = (acc[i][1] + bqk[n_base + 1]) * INVS;
    float v2 = (acc[i][2] + bqk[n_base + 2]) * INVS;
    float v3 = (acc[i][3] + bqk[n_base + 3]) * INVS;
    vf.x = v0; vf.y = v1; vf.z = v2; vf.w = v3;
    vb[0] = (__bf16)v0; vb[1] = (__bf16)v1;
    vb[2] = (__bf16)v2; vb[3] = (__bf16)v3;
    const size_t fidx =
        ((((size_t)(bb * NH + h) * 4 + ks) * 2 + half) * SEQ + ss) * 8 + e;
    if (is_q) {
      *(float4*)(qo + (size_t)m * ALLD + n_base) = vf;
      *(bf16x4*)(qf + fidx) = vb;
    } else {
      *(bf16x4*)(kf + fidx) = vb;
    }
  }
}

// ---------------------------------------------------------------------------
// K2: QR2[b][h][s][id] = sum_d q[b,s,h*64+d] * rel_emb[id,d] * INVS
// One block per (b*S + s); thread = id (256 ids). Transposed layout so K3's
// per-head bias gather (lane=t -> consecutive id) is coalesced.
// ---------------------------------------------------------------------------
__global__ __launch_bounds__(256) void qr_kernel(
    const float* __restrict__ q, const float* __restrict__ rel,
    float* __restrict__ QR) {
  const int bs = blockIdx.x;  // 0..2047
  const int tid = threadIdx.x;
  const int b = bs >> 10;
  const int s = bs & 1023;

  __shared__ float qs[768];
  qs[tid] = q[(size_t)bs * 768 + tid];
  qs[tid + 256] = q[(size_t)bs * 768 + tid + 256];
  qs[tid + 512] = q[(size_t)bs * 768 + tid + 512];
  __syncthreads();

  const float* rrow = rel + (size_t)tid * 64;
  float o[12];
#pragma unroll
  for (int h = 0; h < 12; ++h) o[h] = 0.f;

#pragma unroll
  for (int d4 = 0; d4 < 64; d4 += 4) {
    float4 rv = *(const float4*)(rrow + d4);
#pragma unroll
    for (int h = 0; h < 12; ++h) {
      o[h] += qs[h * 64 + d4 + 0] * rv.x + qs[h * 64 + d4 + 1] * rv.y +
              qs[h * 64 + d4 + 2] * rv.z + qs[h * 64 + d4 + 3] * rv.w;
    }
  }

#pragma unroll
  for (int h = 0; h < 12; ++h) {
    QR[(((size_t)(b * NH + h) << 10) + s) * 256 + tid] = o[h] * INVS;
  }
}

// ---------------------------------------------------------------------------
// K3: fused scores (MFMA) + QR bias + LDS transpose + writer + store.
// Block = 256 thr (4 waves), one 32x32 (s,t) tile, all 12 heads.
// Wave w computes heads 3w..3w+2 (48 acc VGPRs), adds bias (coalesced QR2
// gather), dumps to LDS A2[12][32][32]. After barrier: writer phase with
// lane=(tq,c4) -> 16 lanes cover 64 consecutive channels: dense 256B store
// segments, full cache-line utilization.
// ---------------------------------------------------------------------------
__global__ __launch_bounds__(256, 3) void main_kernel(
    const __bf16* __restrict__ qf, const __bf16* __restrict__ kf,
    const float* __restrict__ QR2, const float* __restrict__ Wout,
    const float* __restrict__ bout, float* __restrict__ out) {
  const int tid = threadIdx.x;
  const int l = tid & 63;
  const int w = tid >> 6;
  const int b = blockIdx.z;
  const int s0 = blockIdx.y * 32;
  const int t0 = blockIdx.x * 32;

  __shared__ float A2[12][32][32];  // 48 KB biased scores [h][s][t]
  __shared__ float Wl[12][64];
  __shared__ float bol[64];
#pragma unroll
  for (int r = 0; r < 3; ++r) ((float*)Wl)[tid + 256 * r] = Wout[tid + 256 * r];
  if (tid < 64) bol[tid] = bout[tid];

  const int half = l >> 5;
  const int lane31 = l & 31;
  const int t = t0 + lane31;

  const bf16x8* qfp = (const bf16x8*)qf;
  const bf16x8* kfp = (const bf16x8*)kf;

  // -------- scores via MFMA: 3 heads per wave, bias folded, dump to LDS ----
#pragma unroll
  for (int hh = 0; hh < 3; ++hh) {
    const int h = w * 3 + hh;
    f32x16 acc;
#pragma unroll
    for (int e = 0; e < 16; ++e) acc[e] = 0.f;
#pragma unroll
    for (int ks = 0; ks < 4; ++ks) {
      const size_t pbase = (((size_t)(b * NH + h) * 4 + ks) * 2 + half) * SEQ;
      bf16x8 af = qfp[pbase + s0 + lane31];
      bf16x8 bv = kfp[pbase + t];
      acc = __builtin_amdgcn_mfma_f32_32x32x16_bf16(af, bv, acc, 0, 0, 0);
    }
    const float* qr2 = QR2 + (((size_t)(b * NH + h) << 10) << 8);
#pragma unroll
    for (int r = 0; r < 16; ++r) {
      const int sl = (r & 3) + 8 * (r >> 2) + 4 * half;
      const int s = s0 + sl;
      const int d = t - s;
      const int id = (d >= 0) ? (d < 127 ? d : 127)
                              : (d > -127 ? d + 256 : 129);
      A2[h][sl][lane31] = acc[r] + qr2[((size_t)s << 8) + id];
    }
  }
  __syncthreads();

  // -------- writer: out[b,s,t,c] = sum_h A2[h,s,t]*W[h,c] + b[c] ----------
  const int c4 = l & 15;
  const int tq = l >> 4;
  float4 w4[12];
#pragma unroll
  for (int h = 0; h < 12; ++h) w4[h] = *(const float4*)&Wl[h][c4 * 4];
  const float4 bo = *(const float4*)&bol[c4 * 4];

  float* obase = out + (((size_t)(b << 10) + s0) << 10) * 64 +
                 (size_t)t0 * 64 + c4 * 4;
#pragma unroll 1
  for (int si = 0; si < 8; ++si) {
    const int sl = w * 8 + si;
#pragma unroll 2
    for (int tt = 0; tt < 8; ++tt) {
      const int tl = tq * 8 + tt;
      float4 o = bo;
#pragma unroll
      for (int h = 0; h < 12; ++h) {
        const float a = A2[h][sl][tl];
        o.x += a * w4[h].x;
        o.y += a * w4[h].y;
        o.z += a * w4[h].z;
        o.w += a * w4[h].w;
      }
      *(float4*)(obase + (((size_t)sl << 10) + tl) * 64) = o;
    }
  }
}

// ---------------------------------------------------------------------------
extern "C" void kernel_launch(void* const* d_in, const int* in_sizes, int n_in,
                              void* d_out, int out_size, void* d_ws,
                              size_t ws_size, hipStream_t stream) {
  const float* p1 = (const float*)d_in[1];
  const float* Wqk = (const float*)d_in[3];
  const float* bqk = (const float*)d_in[4];
  const float* rel = (const float*)d_in[5];
  const float* Wout = (const float*)d_in[6];
  const float* bout = (const float*)d_in[7];
  float* out = (float*)d_out;

  // workspace layout:
  //   qo  fp32 [2*1024*768]            6.29 MB
  //   qf  bf16 frag [2*1024*768]       3.15 MB
  //   kf  bf16 frag [2*1024*768]       3.15 MB
  //   QR2 fp32 [2][12][1024][256]     25.17 MB   (total 37.75 MB)
  float* qo = (float*)d_ws;
  __bf16* qf = (__bf16*)(qo + (size_t)BATCH * SEQ * ALLD);
  __bf16* kf = qf + (size_t)BATCH * SEQ * ALLD;
  float* QR2 = (float*)(kf + (size_t)BATCH * SEQ * ALLD);

  hipLaunchKernelGGL(qk_gemm, dim3(32, 24), dim3(256), 0, stream, p1, Wqk, bqk,
                     qo, qf, kf);
  hipLaunchKernelGGL(qr_kernel, dim3(BATCH * SEQ), dim3(256), 0, stream, qo,
                     rel, QR2);
  hipLaunchKernelGGL(main_kernel, dim3(SEQ / 32, SEQ / 32, BATCH), dim3(256),
                     0, stream, qf, kf, QR2, Wout, bout, out);
}

// Round 4
// 201.909 us; speedup vs baseline: 6.0220x; 1.4251x over previous
//
#include <hip/hip_runtime.h>
#include <math.h>

// Problem constants (B=2, S=1024, H=12, HS=64, ALL=768, P=128)
#define SEQ   1024
#define BATCH 2
#define NH    12
#define ALLD  768
// 1/scaling = 1/64^0.25
#define INVS  0.35355339059327373f

typedef __attribute__((ext_vector_type(8)))  __bf16 bf16x8;
typedef __attribute__((ext_vector_type(16))) float  f32x16;

// ---------------------------------------------------------------------------
// K0: convert p1 / Wqk / rel_emb to bf16 MFMA-fragment layouts.
//   p1f [j=ks*2+half (96)][m (2048)][8]   : p1[m][j*8+e]
//   wf  [j (96)][n (1536)][8]             : Wqk[j*8+e][n]
//   relf[j (8)][id (256)][8]              : rel[id][j*8+e]
// ---------------------------------------------------------------------------
__global__ __launch_bounds__(256) void convert_kernel(
    const float* __restrict__ p1, const float* __restrict__ Wqk,
    const float* __restrict__ rel, __bf16* __restrict__ p1f,
    __bf16* __restrict__ wf, __bf16* __restrict__ relf) {
  const int t = blockIdx.x * 256 + threadIdx.x;
  if (t < 196608) {                       // 2048 * 96
    const int m = t / 96, j = t - m * 96;
    const float* src = p1 + (size_t)m * 768 + j * 8;
    bf16x8 v;
#pragma unroll
    for (int e = 0; e < 8; ++e) v[e] = (__bf16)src[e];
    *(bf16x8*)(p1f + ((size_t)j * 2048 + m) * 8) = v;
  } else if (t < 344064) {                // + 96 * 1536
    const int t2 = t - 196608;
    const int j = t2 / 1536, n = t2 - j * 1536;
    bf16x8 v;
#pragma unroll
    for (int e = 0; e < 8; ++e)
      v[e] = (__bf16)Wqk[(size_t)(j * 8 + e) * 1536 + n];
    *(bf16x8*)(wf + ((size_t)j * 1536 + n) * 8) = v;
  } else if (t < 346112) {                // + 8 * 256
    const int t3 = t - 344064;
    const int id = t3 & 255, j = t3 >> 8;
    const float* src = rel + (size_t)id * 64 + j * 8;
    bf16x8 v;
#pragma unroll
    for (int e = 0; e < 8; ++e) v[e] = (__bf16)src[e];
    *(bf16x8*)(relf + ((size_t)j * 256 + id) * 8) = v;
  }
}

// ---------------------------------------------------------------------------
// K1: u = p1 @ W_qk + b_qk, scaled by INVS; emit q/k in MFMA frag layout.
//   qf/kf [b][h][ks4][half][row][8]
// Block: 4 waves, 128m x 32n; wave w owns rows m0+w*32..+32. 48 K-steps.
// ---------------------------------------------------------------------------
__global__ __launch_bounds__(256, 4) void qk_gemm(
    const __bf16* __restrict__ p1f, const __bf16* __restrict__ wf,
    const float* __restrict__ bqk, __bf16* __restrict__ qf,
    __bf16* __restrict__ kf) {
  const int tid = threadIdx.x;
  const int l = tid & 63, w = tid >> 6;
  const int l31 = l & 31, half = l >> 5;
  const int m0 = blockIdx.x * 128 + w * 32;
  const int n0 = blockIdx.y * 32;

  const bf16x8* ap = (const bf16x8*)p1f;
  const bf16x8* bp = (const bf16x8*)wf;

  f32x16 acc;
#pragma unroll
  for (int e = 0; e < 16; ++e) acc[e] = 0.f;
#pragma unroll 4
  for (int ks = 0; ks < 48; ++ks) {
    bf16x8 af = ap[(size_t)(ks * 2 + half) * 2048 + m0 + l31];
    bf16x8 bv = bp[(size_t)(ks * 2 + half) * 1536 + n0 + l31];
    acc = __builtin_amdgcn_mfma_f32_32x32x16_bf16(af, bv, acc, 0, 0, 0);
  }

  const int n = n0 + l31;
  const float bias = bqk[n];
  const bool is_q = (n < ALLD);
  const int nn = is_q ? n : n - ALLD;
  const int h = nn >> 6, dd = nn & 63;
  const int ks4 = dd >> 4, hf = (dd >> 3) & 1, e = dd & 7;
  __bf16* fdst = is_q ? qf : kf;
#pragma unroll
  for (int r = 0; r < 16; ++r) {
    const int m = m0 + (r & 3) + 8 * (r >> 2) + 4 * half;
    const int bb = m >> 10, ss = m & 1023;
    const float v = (acc[r] + bias) * INVS;
    fdst[((((size_t)(bb * NH + h) * 4 + ks4) * 2 + hf) * SEQ + ss) * 8 + e] =
        (__bf16)v;
  }
}

// ---------------------------------------------------------------------------
// K2: QR2[b][h][s][id] = (q_frag . rel_frag) * INVS  via MFMA.
// Block: 4 waves on id (128), 32 s-rows; grid (2, 32, 24).
// ---------------------------------------------------------------------------
__global__ __launch_bounds__(256, 4) void qr_mfma(
    const __bf16* __restrict__ qf, const __bf16* __restrict__ relf,
    float* __restrict__ QR2) {
  const int tid = threadIdx.x;
  const int l = tid & 63, w = tid >> 6;
  const int l31 = l & 31, half = l >> 5;
  const int bh = blockIdx.z;                   // b*12+h
  const int s0 = blockIdx.y * 32;
  const int id0 = blockIdx.x * 128 + w * 32;

  const bf16x8* ap = (const bf16x8*)qf;
  const bf16x8* bp = (const bf16x8*)relf;

  f32x16 acc;
#pragma unroll
  for (int e = 0; e < 16; ++e) acc[e] = 0.f;
#pragma unroll
  for (int ks = 0; ks < 4; ++ks) {
    bf16x8 af = ap[(size_t)(bh * 8 + ks * 2 + half) * SEQ + s0 + l31];
    bf16x8 bv = bp[(size_t)(ks * 2 + half) * 256 + id0 + l31];
    acc = __builtin_amdgcn_mfma_f32_32x32x16_bf16(af, bv, acc, 0, 0, 0);
  }
  float* dst = QR2 + (((size_t)bh << 10) << 8);
#pragma unroll
  for (int r = 0; r < 16; ++r) {
    const int s = s0 + (r & 3) + 8 * (r >> 2) + 4 * half;
    dst[((size_t)s << 8) + id0 + l31] = acc[r] * INVS;
  }
}

// ---------------------------------------------------------------------------
// K3: QK MFMA scores + QR bias -> P_lds bf16 [1024 pairs][16 h] ->
//     writer MFMA (P @ W_out^T, K padded to 16) -> dense 128B stores.
// Block: 4 waves, one 32x32 (s,t) tile; wave w computes heads 3w..3w+2.
// ---------------------------------------------------------------------------
__global__ __launch_bounds__(256, 4) void main_kernel(
    const __bf16* __restrict__ qf, const __bf16* __restrict__ kf,
    const float* __restrict__ QR2, const float* __restrict__ Wout,
    const float* __restrict__ bout, float* __restrict__ out) {
  const int tid = threadIdx.x;
  const int l = tid & 63, w = tid >> 6;
  const int l31 = l & 31, half = l >> 5;
  const int b = blockIdx.z;
  const int s0 = blockIdx.y * 32;
  const int t0 = blockIdx.x * 32;

  __shared__ __bf16 P[1024][16];  // 32 KB: [pair = sl*32+tl][head]

  // zero the pad heads 12..15 (4 rows per thread, 8B each)
  {
    ushort4 z = {0, 0, 0, 0};
#pragma unroll
    for (int i = 0; i < 4; ++i) *(ushort4*)&P[tid * 4 + i][12] = z;
  }

  // writer B-frag (W2[c][h] = Wout[h][c], padded) + bias, in registers
  bf16x8 wfrag[2];
  float bo[2];
#pragma unroll
  for (int ct = 0; ct < 2; ++ct) {
#pragma unroll
    for (int e = 0; e < 8; ++e) {
      const int hh = half * 8 + e;
      const float v = (hh < NH) ? Wout[hh * 64 + ct * 32 + l31] : 0.f;
      wfrag[ct][e] = (__bf16)v;
    }
    bo[ct] = bout[ct * 32 + l31];
  }

  const bf16x8* qfp = (const bf16x8*)qf;
  const bf16x8* kfp = (const bf16x8*)kf;
  const int t = t0 + l31;

  // -------- QK phase: 3 heads per wave --------
#pragma unroll
  for (int hh = 0; hh < 3; ++hh) {
    const int h = w * 3 + hh;
    f32x16 acc;
#pragma unroll
    for (int e = 0; e < 16; ++e) acc[e] = 0.f;
#pragma unroll
    for (int ks = 0; ks < 4; ++ks) {
      const size_t pbase = (((size_t)(b * NH + h) * 4 + ks) * 2 + half) * SEQ;
      bf16x8 af = qfp[pbase + s0 + l31];
      bf16x8 bv = kfp[pbase + t];
      acc = __builtin_amdgcn_mfma_f32_32x32x16_bf16(af, bv, acc, 0, 0, 0);
    }
    const float* qr2 = QR2 + (((size_t)(b * NH + h) << 10) << 8);
#pragma unroll
    for (int r = 0; r < 16; ++r) {
      const int sl = (r & 3) + 8 * (r >> 2) + 4 * half;
      const int s = s0 + sl;
      const int d = t - s;
      const int id =
          (d >= 0) ? (d < 127 ? d : 127) : (d > -127 ? d + 256 : 129);
      const float v = acc[r] + qr2[((size_t)s << 8) + id];
      P[sl * 32 + l31][h] = (__bf16)v;
    }
  }
  __syncthreads();

  // -------- writer MFMA: [1024 x 16] @ [16 x 64] --------
  float* obase = out + ((((size_t)b << 10) + s0) << 10) * 64 + (size_t)t0 * 64;
#pragma unroll 1
  for (int rt = w; rt < 32; rt += 4) {
    bf16x8 af = *(const bf16x8*)&P[rt * 32 + l31][half * 8];
    f32x16 o0, o1;
#pragma unroll
    for (int e = 0; e < 16; ++e) { o0[e] = 0.f; o1[e] = 0.f; }
    o0 = __builtin_amdgcn_mfma_f32_32x32x16_bf16(af, wfrag[0], o0, 0, 0, 0);
    o1 = __builtin_amdgcn_mfma_f32_32x32x16_bf16(af, wfrag[1], o1, 0, 0, 0);
#pragma unroll
    for (int r = 0; r < 16; ++r) {
      const int p = rt * 32 + (r & 3) + 8 * (r >> 2) + 4 * half;
      const int sl = p >> 5, tl = p & 31;
      float* po = obase + (((size_t)sl << 10) + tl) * 64 + l31;
      po[0] = o0[r] + bo[0];
      po[32] = o1[r] + bo[1];
    }
  }
}

// ---------------------------------------------------------------------------
extern "C" void kernel_launch(void* const* d_in, const int* in_sizes, int n_in,
                              void* d_out, int out_size, void* d_ws,
                              size_t ws_size, hipStream_t stream) {
  const float* p1 = (const float*)d_in[1];
  const float* Wqk = (const float*)d_in[3];
  const float* bqk = (const float*)d_in[4];
  const float* rel = (const float*)d_in[5];
  const float* Wout = (const float*)d_in[6];
  const float* bout = (const float*)d_in[7];
  float* out = (float*)d_out;

  // ws layout (31.5 MB):
  //   qf   bf16 1,572,864 elems  @ 0          (3.15 MB)
  //   kf   bf16 1,572,864 elems  @ 3,145,728  (3.15 MB)
  //   relf bf16 16,384 elems     @ 6,291,456  (32 KB)
  //   QR2  f32  6,291,456 elems  @ 6,324,224  (25.2 MB)
  //     p1f bf16 1,572,864 elems overlaps QR2 head   (dead before K2 writes)
  //     wf  bf16 1,179,648 elems follows p1f
  __bf16* qf = (__bf16*)d_ws;
  __bf16* kf = qf + 1572864;
  __bf16* relf = kf + 1572864;
  float* QR2 = (float*)((char*)d_ws + 6324224);
  __bf16* p1f = (__bf16*)QR2;
  __bf16* wf = p1f + 1572864;

  hipLaunchKernelGGL(convert_kernel, dim3(1352), dim3(256), 0, stream, p1, Wqk,
                     rel, p1f, wf, relf);
  hipLaunchKernelGGL(qk_gemm, dim3(16, 48), dim3(256), 0, stream, p1f, wf, bqk,
                     qf, kf);
  hipLaunchKernelGGL(qr_mfma, dim3(2, 32, BATCH * NH), dim3(256), 0, stream,
                     qf, relf, QR2);
  hipLaunchKernelGGL(main_kernel, dim3(SEQ / 32, SEQ / 32, BATCH), dim3(256),
                     0, stream, qf, kf, QR2, Wout, bout, out);
}

// Round 5
// 191.938 us; speedup vs baseline: 6.3349x; 1.0520x over previous
//
#include <hip/hip_runtime.h>
#include <math.h>

// Problem constants (B=2, S=1024, H=12, HS=64, ALL=768, P=128)
#define SEQ   1024
#define BATCH 2
#define NH    12
#define ALLD  768
// 1/scaling = 1/64^0.25
#define INVS  0.35355339059327373f

typedef __attribute__((ext_vector_type(8)))  __bf16 bf16x8;
typedef __attribute__((ext_vector_type(16))) float  f32x16;

// ---------------------------------------------------------------------------
// K0: convert p1 / Wqk / rel_emb to bf16 MFMA-fragment layouts.
//   p1f [j=ks*2+half (96)][m (2048)][8]   : p1[m][j*8+e]
//   wf  [j (96)][n (1536)][8]             : Wqk[j*8+e][n]
//   relf[j (8)][id (256)][8]              : rel[id][j*8+e]
// ---------------------------------------------------------------------------
__global__ __launch_bounds__(256) void convert_kernel(
    const float* __restrict__ p1, const float* __restrict__ Wqk,
    const float* __restrict__ rel, __bf16* __restrict__ p1f,
    __bf16* __restrict__ wf, __bf16* __restrict__ relf) {
  const int t = blockIdx.x * 256 + threadIdx.x;
  if (t < 196608) {                       // 2048 * 96
    const int m = t / 96, j = t - m * 96;
    const float* src = p1 + (size_t)m * 768 + j * 8;
    bf16x8 v;
#pragma unroll
    for (int e = 0; e < 8; ++e) v[e] = (__bf16)src[e];
    *(bf16x8*)(p1f + ((size_t)j * 2048 + m) * 8) = v;
  } else if (t < 344064) {                // + 96 * 1536
    const int t2 = t - 196608;
    const int j = t2 / 1536, n = t2 - j * 1536;
    bf16x8 v;
#pragma unroll
    for (int e = 0; e < 8; ++e)
      v[e] = (__bf16)Wqk[(size_t)(j * 8 + e) * 1536 + n];
    *(bf16x8*)(wf + ((size_t)j * 1536 + n) * 8) = v;
  } else if (t < 346112) {                // + 8 * 256
    const int t3 = t - 344064;
    const int id = t3 & 255, j = t3 >> 8;
    const float* src = rel + (size_t)id * 64 + j * 8;
    bf16x8 v;
#pragma unroll
    for (int e = 0; e < 8; ++e) v[e] = (__bf16)src[e];
    *(bf16x8*)(relf + ((size_t)j * 256 + id) * 8) = v;
  }
}

// ---------------------------------------------------------------------------
// K1: u = p1 @ W_qk + b_qk, scaled by INVS; emit q/k in MFMA frag layout.
//   qf/kf [b][h][ks4][half][row][8]
// Block: 4 waves as 2(m)x2(n) -> 128m x 64n. Wave: 64m x 32n, 2 acc,
// shared B-frag (loads/MFMA = 1.5). 48 K-steps. Grid (16, 24).
// ---------------------------------------------------------------------------
__global__ __launch_bounds__(256, 4) void qk_gemm(
    const __bf16* __restrict__ p1f, const __bf16* __restrict__ wf,
    const float* __restrict__ bqk, __bf16* __restrict__ qf,
    __bf16* __restrict__ kf) {
  const int tid = threadIdx.x;
  const int l = tid & 63, w = tid >> 6;
  const int l31 = l & 31, half = l >> 5;
  const int m0 = blockIdx.x * 128 + (w >> 1) * 64;
  const int n0 = blockIdx.y * 64 + (w & 1) * 32;

  const bf16x8* ap = (const bf16x8*)p1f;
  const bf16x8* bp = (const bf16x8*)wf;

  f32x16 acc0, acc1;
#pragma unroll
  for (int e = 0; e < 16; ++e) { acc0[e] = 0.f; acc1[e] = 0.f; }
#pragma unroll 4
  for (int ks = 0; ks < 48; ++ks) {
    const size_t ja = (size_t)(ks * 2 + half);
    bf16x8 a0 = ap[ja * 2048 + m0 + l31];
    bf16x8 a1 = ap[ja * 2048 + m0 + 32 + l31];
    bf16x8 bv = bp[ja * 1536 + n0 + l31];
    acc0 = __builtin_amdgcn_mfma_f32_32x32x16_bf16(a0, bv, acc0, 0, 0, 0);
    acc1 = __builtin_amdgcn_mfma_f32_32x32x16_bf16(a1, bv, acc1, 0, 0, 0);
  }

  const int n = n0 + l31;
  const float bias = bqk[n];
  const bool is_q = (n < ALLD);
  const int nn = is_q ? n : n - ALLD;
  const int h = nn >> 6, dd = nn & 63;
  const int ks4 = dd >> 4, hf = (dd >> 3) & 1, e = dd & 7;
  __bf16* fdst = is_q ? qf : kf;
#pragma unroll
  for (int mi = 0; mi < 2; ++mi) {
#pragma unroll
    for (int r = 0; r < 16; ++r) {
      const int m = m0 + mi * 32 + (r & 3) + 8 * (r >> 2) + 4 * half;
      const int bb = m >> 10, ss = m & 1023;
      const float v = ((mi ? acc1[r] : acc0[r]) + bias) * INVS;
      fdst[((((size_t)(bb * NH + h) * 4 + ks4) * 2 + hf) * SEQ + ss) * 8 + e] =
          (__bf16)v;
    }
  }
}

// ---------------------------------------------------------------------------
// K2: QR2[b][h][s][id] = (q . rel) * INVS  via MFMA, stored bf16.
// Block: 4 waves on id (128), 32 s-rows; grid (2, 32, 24).
// ---------------------------------------------------------------------------
__global__ __launch_bounds__(256, 4) void qr_mfma(
    const __bf16* __restrict__ qf, const __bf16* __restrict__ relf,
    __bf16* __restrict__ QR2) {
  const int tid = threadIdx.x;
  const int l = tid & 63, w = tid >> 6;
  const int l31 = l & 31, half = l >> 5;
  const int bh = blockIdx.z;                   // b*12+h
  const int s0 = blockIdx.y * 32;
  const int id0 = blockIdx.x * 128 + w * 32;

  const bf16x8* ap = (const bf16x8*)qf;
  const bf16x8* bp = (const bf16x8*)relf;

  f32x16 acc;
#pragma unroll
  for (int e = 0; e < 16; ++e) acc[e] = 0.f;
#pragma unroll
  for (int ks = 0; ks < 4; ++ks) {
    bf16x8 af = ap[(size_t)(bh * 8 + ks * 2 + half) * SEQ + s0 + l31];
    bf16x8 bv = bp[(size_t)(ks * 2 + half) * 256 + id0 + l31];
    acc = __builtin_amdgcn_mfma_f32_32x32x16_bf16(af, bv, acc, 0, 0, 0);
  }
  __bf16* dst = QR2 + ((size_t)bh << 18);
#pragma unroll
  for (int r = 0; r < 16; ++r) {
    const int s = s0 + (r & 3) + 8 * (r >> 2) + 4 * half;
    dst[((size_t)s << 8) + id0 + l31] = (__bf16)(acc[r] * INVS);
  }
}

// ---------------------------------------------------------------------------
// K3: QK MFMA scores + bf16 QR bias -> P_lds bf16 [1024 pairs][16 h] ->
//     writer MFMA (P @ W_out^T, K padded to 16, even/odd col interleave)
//     -> float2 stores (dense 256B segments).
// XCD-bijective swizzle: each XCD owns a contiguous chunk of s-blocks ->
// QR2/kf slices stay L2-resident.
// ---------------------------------------------------------------------------
__global__ __launch_bounds__(256, 4) void main_kernel(
    const __bf16* __restrict__ qf, const __bf16* __restrict__ kf,
    const __bf16* __restrict__ QR2, const float* __restrict__ Wout,
    const float* __restrict__ bout, float* __restrict__ out) {
  const int tid = threadIdx.x;
  const int l = tid & 63, w = tid >> 6;
  const int l31 = l & 31, half = l >> 5;

  // bijective XCD swizzle (nwg = 2048, divisible by 8)
  const int raw = blockIdx.x + (blockIdx.y << 5) + (blockIdx.z << 10);
  const int swz = (raw & 7) * 256 + (raw >> 3);
  const int t0 = (swz & 31) * 32;
  const int s0 = ((swz >> 5) & 31) * 32;
  const int b = swz >> 10;

  __shared__ __bf16 P[1024][16];  // 32 KB: [pair = sl*32+tl][head]

  // zero the pad heads 12..15
  {
    ushort4 z = {0, 0, 0, 0};
#pragma unroll
    for (int i = 0; i < 4; ++i) *(ushort4*)&P[tid * 4 + i][12] = z;
  }

  // writer B-frags: even/odd channel interleave. B[k=half*8+e][col=l31]:
  //   wfrag0 -> c = 2*l31, wfrag1 -> c = 2*l31+1
  bf16x8 wfrag0, wfrag1;
#pragma unroll
  for (int e = 0; e < 8; ++e) {
    const int hh = half * 8 + e;
    wfrag0[e] = (__bf16)((hh < NH) ? Wout[hh * 64 + 2 * l31] : 0.f);
    wfrag1[e] = (__bf16)((hh < NH) ? Wout[hh * 64 + 2 * l31 + 1] : 0.f);
  }
  const float bo0 = bout[2 * l31];
  const float bo1 = bout[2 * l31 + 1];

  const bf16x8* qfp = (const bf16x8*)qf;
  const bf16x8* kfp = (const bf16x8*)kf;
  const int t = t0 + l31;

  // -------- QK phase: 3 heads per wave --------
#pragma unroll
  for (int hh = 0; hh < 3; ++hh) {
    const int h = w * 3 + hh;
    f32x16 acc;
#pragma unroll
    for (int e = 0; e < 16; ++e) acc[e] = 0.f;
#pragma unroll
    for (int ks = 0; ks < 4; ++ks) {
      const size_t pbase = (((size_t)(b * NH + h) * 4 + ks) * 2 + half) * SEQ;
      bf16x8 af = qfp[pbase + s0 + l31];
      bf16x8 bv = kfp[pbase + t];
      acc = __builtin_amdgcn_mfma_f32_32x32x16_bf16(af, bv, acc, 0, 0, 0);
    }
    const __bf16* qr2 = QR2 + ((size_t)(b * NH + h) << 18);
#pragma unroll
    for (int r = 0; r < 16; ++r) {
      const int sl = (r & 3) + 8 * (r >> 2) + 4 * half;
      const int s = s0 + sl;
      const int d = t - s;
      const int id =
          (d >= 0) ? (d < 127 ? d : 127) : (d > -127 ? d + 256 : 129);
      const float v = acc[r] + (float)qr2[((size_t)s << 8) + id];
      P[sl * 32 + l31][h] = (__bf16)v;
    }
  }
  __syncthreads();

  // -------- writer MFMA: [1024 x 16] @ [16 x 64] --------
  float* obase = out + ((((size_t)b << 10) + s0) << 10) * 64 + (size_t)t0 * 64;
#pragma unroll 1
  for (int rt = w; rt < 32; rt += 4) {
    bf16x8 af = *(const bf16x8*)&P[rt * 32 + l31][half * 8];
    f32x16 o0, o1;
#pragma unroll
    for (int e = 0; e < 16; ++e) { o0[e] = 0.f; o1[e] = 0.f; }
    o0 = __builtin_amdgcn_mfma_f32_32x32x16_bf16(af, wfrag0, o0, 0, 0, 0);
    o1 = __builtin_amdgcn_mfma_f32_32x32x16_bf16(af, wfrag1, o1, 0, 0, 0);
    float* orow = obase + ((size_t)rt << 16) + 2 * l31;   // [sl=rt][...]
#pragma unroll
    for (int r = 0; r < 16; ++r) {
      const int tl = (r & 3) + 8 * (r >> 2) + 4 * half;
      float2 v;
      v.x = o0[r] + bo0;
      v.y = o1[r] + bo1;
      *(float2*)(orow + ((size_t)tl << 6)) = v;
    }
  }
}

// ---------------------------------------------------------------------------
extern "C" void kernel_launch(void* const* d_in, const int* in_sizes, int n_in,
                              void* d_out, int out_size, void* d_ws,
                              size_t ws_size, hipStream_t stream) {
  const float* p1 = (const float*)d_in[1];
  const float* Wqk = (const float*)d_in[3];
  const float* bqk = (const float*)d_in[4];
  const float* rel = (const float*)d_in[5];
  const float* Wout = (const float*)d_in[6];
  const float* bout = (const float*)d_in[7];
  float* out = (float*)d_out;

  // ws layout:
  //   qf   bf16 1,572,864 elems  @ 0          (3.15 MB)
  //   kf   bf16 1,572,864 elems  @ 3,145,728  (3.15 MB)
  //   relf bf16 16,384 elems     @ 6,291,456  (32 KB)
  //   QR2  bf16 6,291,456 elems  @ 6,324,224  (12.6 MB)
  //     p1f bf16 1,572,864 elems overlaps QR2 head   (dead before K2 writes)
  //     wf  bf16 1,179,648 elems follows p1f  (total overlap 5.5 MB < 12.6)
  __bf16* qf = (__bf16*)d_ws;
  __bf16* kf = qf + 1572864;
  __bf16* relf = kf + 1572864;
  __bf16* QR2 = (__bf16*)((char*)d_ws + 6324224);
  __bf16* p1f = (__bf16*)QR2;
  __bf16* wf = p1f + 1572864;

  hipLaunchKernelGGL(convert_kernel, dim3(1352), dim3(256), 0, stream, p1, Wqk,
                     rel, p1f, wf, relf);
  hipLaunchKernelGGL(qk_gemm, dim3(16, 24), dim3(256), 0, stream, p1f, wf, bqk,
                     qf, kf);
  hipLaunchKernelGGL(qr_mfma, dim3(2, 32, BATCH * NH), dim3(256), 0, stream,
                     qf, relf, QR2);
  hipLaunchKernelGGL(main_kernel, dim3(SEQ / 32, SEQ / 32, BATCH), dim3(256),
                     0, stream, qf, kf, QR2, Wout, bout, out);
}

// Round 6
// 181.153 us; speedup vs baseline: 6.7120x; 1.0595x over previous
//
#include <hip/hip_runtime.h>
#include <math.h>

// Problem constants (B=2, S=1024, H=12, HS=64, ALL=768, P=128)
#define SEQ   1024
#define BATCH 2
#define NH    12
#define ALLD  768
// 1/scaling = 1/64^0.25
#define INVS  0.35355339059327373f

typedef __attribute__((ext_vector_type(8)))  __bf16 bf16x8;
typedef __attribute__((ext_vector_type(16))) float  f32x16;

// ---------------------------------------------------------------------------
// K0: convert p1 / Wqk / rel_emb to bf16 MFMA-fragment layouts.
//   p1f [j=ks*2+half (96)][m (2048)][8]   : p1[m][j*8+e]
//   wf  [j (96)][n (1536)][8]             : Wqk[j*8+e][n]
//   relf[j (8)][id (256)][8]              : rel[id][j*8+e]
// ---------------------------------------------------------------------------
__global__ __launch_bounds__(256) void convert_kernel(
    const float* __restrict__ p1, const float* __restrict__ Wqk,
    const float* __restrict__ rel, __bf16* __restrict__ p1f,
    __bf16* __restrict__ wf, __bf16* __restrict__ relf) {
  const int t = blockIdx.x * 256 + threadIdx.x;
  if (t < 196608) {                       // 2048 * 96
    const int m = t / 96, j = t - m * 96;
    const float* src = p1 + (size_t)m * 768 + j * 8;
    bf16x8 v;
#pragma unroll
    for (int e = 0; e < 8; ++e) v[e] = (__bf16)src[e];
    *(bf16x8*)(p1f + ((size_t)j * 2048 + m) * 8) = v;
  } else if (t < 344064) {                // + 96 * 1536
    const int t2 = t - 196608;
    const int j = t2 / 1536, n = t2 - j * 1536;
    bf16x8 v;
#pragma unroll
    for (int e = 0; e < 8; ++e)
      v[e] = (__bf16)Wqk[(size_t)(j * 8 + e) * 1536 + n];
    *(bf16x8*)(wf + ((size_t)j * 1536 + n) * 8) = v;
  } else if (t < 346112) {                // + 8 * 256
    const int t3 = t - 344064;
    const int id = t3 & 255, j = t3 >> 8;
    const float* src = rel + (size_t)id * 64 + j * 8;
    bf16x8 v;
#pragma unroll
    for (int e = 0; e < 8; ++e) v[e] = (__bf16)src[e];
    *(bf16x8*)(relf + ((size_t)j * 256 + id) * 8) = v;
  }
}

// ---------------------------------------------------------------------------
// K1: u = p1 @ W_qk + b_qk, scaled by INVS; emit q/k in MFMA frag layout.
//   qf/kf [b][h][ks4][half][row][8]
// Block: 4 waves as 2(m)x2(n) -> 64m x 64n, 1 acc/wave.
// Grid (32, 24) = 768 blocks = 3 blocks/CU -> TLP hides load latency.
// ---------------------------------------------------------------------------
__global__ __launch_bounds__(256) void qk_gemm(
    const __bf16* __restrict__ p1f, const __bf16* __restrict__ wf,
    const float* __restrict__ bqk, __bf16* __restrict__ qf,
    __bf16* __restrict__ kf) {
  const int tid = threadIdx.x;
  const int l = tid & 63, w = tid >> 6;
  const int l31 = l & 31, half = l >> 5;
  const int m0 = blockIdx.x * 64 + (w >> 1) * 32;
  const int n0 = blockIdx.y * 64 + (w & 1) * 32;

  const bf16x8* ap = (const bf16x8*)p1f;
  const bf16x8* bp = (const bf16x8*)wf;

  f32x16 acc;
#pragma unroll
  for (int e = 0; e < 16; ++e) acc[e] = 0.f;
#pragma unroll 8
  for (int ks = 0; ks < 48; ++ks) {
    const size_t ja = (size_t)(ks * 2 + half);
    bf16x8 af = ap[ja * 2048 + m0 + l31];
    bf16x8 bv = bp[ja * 1536 + n0 + l31];
    acc = __builtin_amdgcn_mfma_f32_32x32x16_bf16(af, bv, acc, 0, 0, 0);
  }

  const int n = n0 + l31;
  const float bias = bqk[n];
  const bool is_q = (n < ALLD);
  const int nn = is_q ? n : n - ALLD;
  const int h = nn >> 6, dd = nn & 63;
  const int ks4 = dd >> 4, hf = (dd >> 3) & 1, e = dd & 7;
  __bf16* fdst = is_q ? qf : kf;
#pragma unroll
  for (int r = 0; r < 16; ++r) {
    const int m = m0 + (r & 3) + 8 * (r >> 2) + 4 * half;
    const int bb = m >> 10, ss = m & 1023;
    const float v = (acc[r] + bias) * INVS;
    fdst[((((size_t)(bb * NH + h) * 4 + ks4) * 2 + hf) * SEQ + ss) * 8 + e] =
        (__bf16)v;
  }
}

// ---------------------------------------------------------------------------
// K2: QR2[b][h][s][id] = (q . rel) * INVS  via MFMA, stored bf16.
// Block: 4 waves on id (128), 32 s-rows; grid (2, 32, 24).
// ---------------------------------------------------------------------------
__global__ __launch_bounds__(256, 4) void qr_mfma(
    const __bf16* __restrict__ qf, const __bf16* __restrict__ relf,
    __bf16* __restrict__ QR2) {
  const int tid = threadIdx.x;
  const int l = tid & 63, w = tid >> 6;
  const int l31 = l & 31, half = l >> 5;
  const int bh = blockIdx.z;                   // b*12+h
  const int s0 = blockIdx.y * 32;
  const int id0 = blockIdx.x * 128 + w * 32;

  const bf16x8* ap = (const bf16x8*)qf;
  const bf16x8* bp = (const bf16x8*)relf;

  f32x16 acc;
#pragma unroll
  for (int e = 0; e < 16; ++e) acc[e] = 0.f;
#pragma unroll
  for (int ks = 0; ks < 4; ++ks) {
    bf16x8 af = ap[(size_t)(bh * 8 + ks * 2 + half) * SEQ + s0 + l31];
    bf16x8 bv = bp[(size_t)(ks * 2 + half) * 256 + id0 + l31];
    acc = __builtin_amdgcn_mfma_f32_32x32x16_bf16(af, bv, acc, 0, 0, 0);
  }
  __bf16* dst = QR2 + ((size_t)bh << 18);
#pragma unroll
  for (int r = 0; r < 16; ++r) {
    const int s = s0 + (r & 3) + 8 * (r >> 2) + 4 * half;
    dst[((size_t)s << 8) + id0 + l31] = (__bf16)(acc[r] * INVS);
  }
}

// ---------------------------------------------------------------------------
// K3: QK MFMA scores + bf16 QR bias -> P_lds bf16 [1024 pairs][20 (16h+pad)]
//     (40B rows: bank start pair*10%32, 16 distinct -> 2-way = free) ->
//     writer MFMA (P @ W_out^T, K padded to 16, even/odd col interleave)
//     -> float2 stores (dense 256B segments).
// XCD-bijective swizzle keeps QR2/kf slices L2-resident.
// ---------------------------------------------------------------------------
__global__ __launch_bounds__(256, 4) void main_kernel(
    const __bf16* __restrict__ qf, const __bf16* __restrict__ kf,
    const __bf16* __restrict__ QR2, const float* __restrict__ Wout,
    const float* __restrict__ bout, float* __restrict__ out) {
  const int tid = threadIdx.x;
  const int l = tid & 63, w = tid >> 6;
  const int l31 = l & 31, half = l >> 5;

  // bijective XCD swizzle (nwg = 2048, divisible by 8)
  const int raw = blockIdx.x + (blockIdx.y << 5) + (blockIdx.z << 10);
  const int swz = (raw & 7) * 256 + (raw >> 3);
  const int t0 = (swz & 31) * 32;
  const int s0 = ((swz >> 5) & 31) * 32;
  const int b = swz >> 10;

  __shared__ __bf16 P[1024][20];  // 40 KB, padded rows -> conflict-free

  // zero the pad heads 12..15
  {
    ushort4 z = {0, 0, 0, 0};
#pragma unroll
    for (int i = 0; i < 4; ++i) *(ushort4*)&P[tid * 4 + i][12] = z;
  }

  // writer B-frags: even/odd channel interleave. B[k=half*8+e][col=l31]:
  //   wfrag0 -> c = 2*l31, wfrag1 -> c = 2*l31+1
  bf16x8 wfrag0, wfrag1;
#pragma unroll
  for (int e = 0; e < 8; ++e) {
    const int hh = half * 8 + e;
    wfrag0[e] = (__bf16)((hh < NH) ? Wout[hh * 64 + 2 * l31] : 0.f);
    wfrag1[e] = (__bf16)((hh < NH) ? Wout[hh * 64 + 2 * l31 + 1] : 0.f);
  }
  const float bo0 = bout[2 * l31];
  const float bo1 = bout[2 * l31 + 1];

  const bf16x8* qfp = (const bf16x8*)qf;
  const bf16x8* kfp = (const bf16x8*)kf;
  const int t = t0 + l31;

  // -------- QK phase: 3 heads per wave --------
#pragma unroll
  for (int hh = 0; hh < 3; ++hh) {
    const int h = w * 3 + hh;
    f32x16 acc;
#pragma unroll
    for (int e = 0; e < 16; ++e) acc[e] = 0.f;
#pragma unroll
    for (int ks = 0; ks < 4; ++ks) {
      const size_t pbase = (((size_t)(b * NH + h) * 4 + ks) * 2 + half) * SEQ;
      bf16x8 af = qfp[pbase + s0 + l31];
      bf16x8 bv = kfp[pbase + t];
      acc = __builtin_amdgcn_mfma_f32_32x32x16_bf16(af, bv, acc, 0, 0, 0);
    }
    const __bf16* qr2 = QR2 + ((size_t)(b * NH + h) << 18);
#pragma unroll
    for (int r = 0; r < 16; ++r) {
      const int sl = (r & 3) + 8 * (r >> 2) + 4 * half;
      const int s = s0 + sl;
      const int d = t - s;
      const int id =
          (d >= 0) ? (d < 127 ? d : 127) : (d > -127 ? d + 256 : 129);
      const float v = acc[r] + (float)qr2[((size_t)s << 8) + id];
      P[sl * 32 + l31][h] = (__bf16)v;
    }
  }
  __syncthreads();

  // -------- writer MFMA: [1024 x 16] @ [16 x 64] --------
  float* obase = out + ((((size_t)b << 10) + s0) << 10) * 64 + (size_t)t0 * 64;
#pragma unroll 1
  for (int rt = w; rt < 32; rt += 4) {
    bf16x8 af = *(const bf16x8*)&P[rt * 32 + l31][half * 8];
    f32x16 o0, o1;
#pragma unroll
    for (int e = 0; e < 16; ++e) { o0[e] = 0.f; o1[e] = 0.f; }
    o0 = __builtin_amdgcn_mfma_f32_32x32x16_bf16(af, wfrag0, o0, 0, 0, 0);
    o1 = __builtin_amdgcn_mfma_f32_32x32x16_bf16(af, wfrag1, o1, 0, 0, 0);
    float* orow = obase + ((size_t)rt << 16) + 2 * l31;   // [sl=rt][...]
#pragma unroll
    for (int r = 0; r < 16; ++r) {
      const int tl = (r & 3) + 8 * (r >> 2) + 4 * half;
      float2 v;
      v.x = o0[r] + bo0;
      v.y = o1[r] + bo1;
      *(float2*)(orow + ((size_t)tl << 6)) = v;
    }
  }
}

// ---------------------------------------------------------------------------
extern "C" void kernel_launch(void* const* d_in, const int* in_sizes, int n_in,
                              void* d_out, int out_size, void* d_ws,
                              size_t ws_size, hipStream_t stream) {
  const float* p1 = (const float*)d_in[1];
  const float* Wqk = (const float*)d_in[3];
  const float* bqk = (const float*)d_in[4];
  const float* rel = (const float*)d_in[5];
  const float* Wout = (const float*)d_in[6];
  const float* bout = (const float*)d_in[7];
  float* out = (float*)d_out;

  // ws layout:
  //   qf   bf16 1,572,864 elems  @ 0          (3.15 MB)
  //   kf   bf16 1,572,864 elems  @ 3,145,728  (3.15 MB)
  //   relf bf16 16,384 elems     @ 6,291,456  (32 KB)
  //   QR2  bf16 6,291,456 elems  @ 6,324,224  (12.6 MB)
  //     p1f bf16 1,572,864 elems overlaps QR2 head   (dead before K2 writes)
  //     wf  bf16 1,179,648 elems follows p1f  (total overlap 5.5 MB < 12.6)
  __bf16* qf = (__bf16*)d_ws;
  __bf16* kf = qf + 1572864;
  __bf16* relf = kf + 1572864;
  __bf16* QR2 = (__bf16*)((char*)d_ws + 6324224);
  __bf16* p1f = (__bf16*)QR2;
  __bf16* wf = p1f + 1572864;

  hipLaunchKernelGGL(convert_kernel, dim3(1352), dim3(256), 0, stream, p1, Wqk,
                     rel, p1f, wf, relf);
  hipLaunchKernelGGL(qk_gemm, dim3(32, 24), dim3(256), 0, stream, p1f, wf, bqk,
                     qf, kf);
  hipLaunchKernelGGL(qr_mfma, dim3(2, 32, BATCH * NH), dim3(256), 0, stream,
                     qf, relf, QR2);
  hipLaunchKernelGGL(main_kernel, dim3(SEQ / 32, SEQ / 32, BATCH), dim3(256),
                     0, stream, qf, kf, QR2, Wout, bout, out);
}

// Round 7
// 134.745 us; speedup vs baseline: 9.0237x; 1.3444x over previous
//
#include <hip/hip_runtime.h>
#include <math.h>

// Problem constants (B=2, S=1024, H=12, HS=64, ALL=768, P=128)
#define SEQ   1024
#define BATCH 2
#define NH    12
#define ALLD  768
// 1/scaling = 1/64^0.25
#define INVS  0.35355339059327373f

typedef __attribute__((ext_vector_type(8)))  __bf16 bf16x8;
typedef __attribute__((ext_vector_type(16))) float  f32x16;
typedef __attribute__((ext_vector_type(2)))  float  f32x2;

// ---------------------------------------------------------------------------
// K1: u = p1 @ W_qk + b_qk, scaled by INVS; emit q/k in MFMA frag layout.
//   qf/kf [b][h][ks4][half][row][8]   (bf16)
// Reads fp32 inputs directly (convert fused):
//   - A (p1): LDS-staged 64x64 fp32 chunk -> in-reg cvt -> bf16 frag LDS.
//   - B (Wqk): frags direct from global; per element e the 64 lanes read
//     consecutive n -> dense 256B coalesced dword loads (L2-hot).
// Block: 4 waves as 2(m)x2(n) -> 64m x 64n. Grid (32, 24).
// ---------------------------------------------------------------------------
__global__ __launch_bounds__(256) void qk_gemm(
    const float* __restrict__ p1, const float* __restrict__ Wqk,
    const float* __restrict__ bqk, __bf16* __restrict__ qf,
    __bf16* __restrict__ kf) {
  const int tid = threadIdx.x;
  const int l = tid & 63, w = tid >> 6;
  const int l31 = l & 31, half = l >> 5;
  const int m0 = blockIdx.x * 64;
  const int mw = (w >> 1) * 32;
  const int nw = blockIdx.y * 64 + (w & 1) * 32;

  __shared__ __bf16 Af[8][66][8];  // 8448 B, padded rows -> conflict-free

  f32x16 acc;
#pragma unroll
  for (int e = 0; e < 16; ++e) acc[e] = 0.f;

  const int arow = tid >> 2;       // 0..63
  const int aq = tid & 3;          // k-quarter (16 floats)

  for (int kk = 0; kk < 768; kk += 64) {
    __syncthreads();  // WAR on Af
    // stage A chunk 64m x 64k fp32 -> bf16 frags
    {
      const float* ap = p1 + (size_t)(m0 + arow) * 768 + kk + aq * 16;
      float4 a0 = ((const float4*)ap)[0];
      float4 a1 = ((const float4*)ap)[1];
      float4 a2 = ((const float4*)ap)[2];
      float4 a3 = ((const float4*)ap)[3];
      bf16x8 f0, f1;
      f0[0] = (__bf16)a0.x; f0[1] = (__bf16)a0.y;
      f0[2] = (__bf16)a0.z; f0[3] = (__bf16)a0.w;
      f0[4] = (__bf16)a1.x; f0[5] = (__bf16)a1.y;
      f0[6] = (__bf16)a1.z; f0[7] = (__bf16)a1.w;
      f1[0] = (__bf16)a2.x; f1[1] = (__bf16)a2.y;
      f1[2] = (__bf16)a2.z; f1[3] = (__bf16)a2.w;
      f1[4] = (__bf16)a3.x; f1[5] = (__bf16)a3.y;
      f1[6] = (__bf16)a3.z; f1[7] = (__bf16)a3.w;
      *(bf16x8*)&Af[aq * 2 + 0][arow][0] = f0;
      *(bf16x8*)&Af[aq * 2 + 1][arow][0] = f1;
    }
    __syncthreads();
#pragma unroll
    for (int ksl = 0; ksl < 4; ++ksl) {
      // B frag: Wqk[kk + ksl*16 + half*8 + e][nw + l31]
      const float* bsrc =
          Wqk + (size_t)(kk + ksl * 16 + half * 8) * 1536 + nw + l31;
      bf16x8 bf;
#pragma unroll
      for (int e = 0; e < 8; ++e) bf[e] = (__bf16)bsrc[(size_t)e * 1536];
      bf16x8 af = *(const bf16x8*)&Af[ksl * 2 + half][mw + l31][0];
      acc = __builtin_amdgcn_mfma_f32_32x32x16_bf16(af, bf, acc, 0, 0, 0);
    }
  }

  const int n = nw + l31;
  const float bias = bqk[n];
  const bool is_q = (n < ALLD);
  const int nn = is_q ? n : n - ALLD;
  const int h = nn >> 6, dd = nn & 63;
  const int ks4 = dd >> 4, hf = (dd >> 3) & 1, e = dd & 7;
  __bf16* fdst = is_q ? qf : kf;
#pragma unroll
  for (int r = 0; r < 16; ++r) {
    const int m = m0 + mw + (r & 3) + 8 * (r >> 2) + 4 * half;
    const int bb = m >> 10, ss = m & 1023;
    const float v = (acc[r] + bias) * INVS;
    fdst[((((size_t)(bb * NH + h) * 4 + ks4) * 2 + hf) * SEQ + ss) * 8 + e] =
        (__bf16)v;
  }
}

// ---------------------------------------------------------------------------
// K2: fused scores + in-tile rel bias + writer + nt-store.
// Per block (b, s0, t0): only ids id(D-32 .. D+31), D = t0-s0, are needed.
// Stage those 64 rel rows in LDS (unioned with P), build 8 bias B-frags,
// reuse q A-frags for QK and bias MFMAs. Bias value for (sl, tl) lives at
// panel col c = tl-sl+32 -> 2x __shfl rotate + select.
// Writer: P @ W_out^T MFMA (K padded to 16), nontemporal float2 stores.
// ---------------------------------------------------------------------------
__global__ __launch_bounds__(256, 4) void main_kernel(
    const __bf16* __restrict__ qf, const __bf16* __restrict__ kf,
    const float* __restrict__ rel, const float* __restrict__ Wout,
    const float* __restrict__ bout, float* __restrict__ out) {
  const int tid = threadIdx.x;
  const int l = tid & 63, w = tid >> 6;
  const int l31 = l & 31, half = l >> 5;

  // bijective XCD swizzle (nwg = 2048, divisible by 8)
  const int raw = blockIdx.x + (blockIdx.y << 5) + (blockIdx.z << 10);
  const int swz = (raw & 7) * 256 + (raw >> 3);
  const int t0 = (swz & 31) * 32;
  const int s0 = ((swz >> 5) & 31) * 32;
  const int b = swz >> 10;
  const int D = t0 - s0;

  // LDS union: rel_s[64][66] f32 (16.9 KB) then P[1024][20] bf16 (40 KB)
  __shared__ __attribute__((aligned(16))) char smem[40960];
  float(*rel_s)[66] = (float(*)[66])smem;
  __bf16(*P)[20] = (__bf16(*)[20])smem;

  // ---- stage the 64 rel rows this tile needs (panel col c <-> d = D-32+c)
  {
    const int c = tid >> 2, q = tid & 3;
    const int d = D - 32 + c;
    const int id = (d >= 0) ? (d < 127 ? d : 127) : (d > -127 ? d + 256 : 129);
    const float4* src = (const float4*)(rel + (size_t)id * 64 + q * 16);
    float4* dst = (float4*)&rel_s[c][q * 16];
#pragma unroll
    for (int i = 0; i < 4; ++i) dst[i] = src[i];
  }
  __syncthreads();

  // ---- build bias B-frags: relfrag[ks][cb], col c = cb*32 + l31
  bf16x8 relfrag[4][2];
#pragma unroll
  for (int ks = 0; ks < 4; ++ks) {
#pragma unroll
    for (int cb = 0; cb < 2; ++cb) {
      const int c = cb * 32 + l31;
      const int base = ks * 16 + half * 8;
      float4 r0 = *(const float4*)&rel_s[c][base];
      float4 r1 = *(const float4*)&rel_s[c][base + 4];
      bf16x8 f;
      f[0] = (__bf16)r0.x; f[1] = (__bf16)r0.y;
      f[2] = (__bf16)r0.z; f[3] = (__bf16)r0.w;
      f[4] = (__bf16)r1.x; f[5] = (__bf16)r1.y;
      f[6] = (__bf16)r1.z; f[7] = (__bf16)r1.w;
      relfrag[ks][cb] = f;
    }
  }
  __syncthreads();  // rel_s dead; P region live from here

  // zero the pad heads 12..15
  {
    ushort4 z = {0, 0, 0, 0};
#pragma unroll
    for (int i = 0; i < 4; ++i) *(ushort4*)&P[tid * 4 + i][12] = z;
  }

  const bf16x8* qfp = (const bf16x8*)qf;
  const bf16x8* kfp = (const bf16x8*)kf;

  // -------- QK + bias phase: 3 heads per wave --------
#pragma unroll
  for (int hh = 0; hh < 3; ++hh) {
    const int h = w * 3 + hh;
    f32x16 acc, bacc0, bacc1;
#pragma unroll
    for (int e = 0; e < 16; ++e) { acc[e] = 0.f; bacc0[e] = 0.f; bacc1[e] = 0.f; }
#pragma unroll
    for (int ks = 0; ks < 4; ++ks) {
      const size_t pbase = (((size_t)(b * NH + h) * 4 + ks) * 2 + half) * SEQ;
      bf16x8 af = qfp[pbase + s0 + l31];
      bf16x8 bvk = kfp[pbase + t0 + l31];
      acc = __builtin_amdgcn_mfma_f32_32x32x16_bf16(af, bvk, acc, 0, 0, 0);
      bacc0 = __builtin_amdgcn_mfma_f32_32x32x16_bf16(af, relfrag[ks][0],
                                                      bacc0, 0, 0, 0);
      bacc1 = __builtin_amdgcn_mfma_f32_32x32x16_bf16(af, relfrag[ks][1],
                                                      bacc1, 0, 0, 0);
    }
#pragma unroll
    for (int r = 0; r < 16; ++r) {
      const int sl = (r & 3) + 8 * (r >> 2) + 4 * half;
      const int src = (l31 - sl) & 31;
      const float v0 = __shfl(bacc0[r], src, 32);
      const float v1 = __shfl(bacc1[r], src, 32);
      const float bias = (l31 >= sl) ? v1 : v0;
      const float v = acc[r] + bias * INVS;
      P[sl * 32 + l31][h] = (__bf16)v;
    }
  }
  __syncthreads();

  // -------- writer MFMA: [1024 x 16] @ [16 x 64] --------
  // B-frags: even/odd channel interleave -> lane owns c = 2*l31, 2*l31+1
  bf16x8 wfrag0, wfrag1;
#pragma unroll
  for (int e = 0; e < 8; ++e) {
    const int hh = half * 8 + e;
    wfrag0[e] = (__bf16)((hh < NH) ? Wout[hh * 64 + 2 * l31] : 0.f);
    wfrag1[e] = (__bf16)((hh < NH) ? Wout[hh * 64 + 2 * l31 + 1] : 0.f);
  }
  const float bo0 = bout[2 * l31];
  const float bo1 = bout[2 * l31 + 1];

  float* obase = out + ((((size_t)b << 10) + s0) << 10) * 64 + (size_t)t0 * 64;
#pragma unroll 1
  for (int rt = w; rt < 32; rt += 4) {
    bf16x8 af = *(const bf16x8*)&P[rt * 32 + l31][half * 8];
    f32x16 o0, o1;
#pragma unroll
    for (int e = 0; e < 16; ++e) { o0[e] = 0.f; o1[e] = 0.f; }
    o0 = __builtin_amdgcn_mfma_f32_32x32x16_bf16(af, wfrag0, o0, 0, 0, 0);
    o1 = __builtin_amdgcn_mfma_f32_32x32x16_bf16(af, wfrag1, o1, 0, 0, 0);
    float* orow = obase + ((size_t)rt << 16) + 2 * l31;  // [sl=rt][...]
#pragma unroll
    for (int r = 0; r < 16; ++r) {
      const int tl = (r & 3) + 8 * (r >> 2) + 4 * half;
      f32x2 v;
      v.x = o0[r] + bo0;
      v.y = o1[r] + bo1;
      __builtin_nontemporal_store(v, (f32x2*)(orow + ((size_t)tl << 6)));
    }
  }
}

// ---------------------------------------------------------------------------
extern "C" void kernel_launch(void* const* d_in, const int* in_sizes, int n_in,
                              void* d_out, int out_size, void* d_ws,
                              size_t ws_size, hipStream_t stream) {
  const float* p1 = (const float*)d_in[1];
  const float* Wqk = (const float*)d_in[3];
  const float* bqk = (const float*)d_in[4];
  const float* rel = (const float*)d_in[5];
  const float* Wout = (const float*)d_in[6];
  const float* bout = (const float*)d_in[7];
  float* out = (float*)d_out;

  // ws layout: qf bf16 [2*12*4*2*1024*8] (3.15 MB) | kf same (3.15 MB)
  __bf16* qf = (__bf16*)d_ws;
  __bf16* kf = qf + 1572864;

  hipLaunchKernelGGL(qk_gemm, dim3(32, 24), dim3(256), 0, stream, p1, Wqk, bqk,
                     qf, kf);
  hipLaunchKernelGGL(main_kernel, dim3(SEQ / 32, SEQ / 32, BATCH), dim3(256),
                     0, stream, qf, kf, rel, Wout, bout, out);
}